// Round 9
// baseline (86.515 us; speedup 1.0000x reference)
//
#include <hip/hip_runtime.h>
#include <hip/hip_bf16.h>

// ---------------------------------------------------------------------------
// BlockedMLP: out = (relu(bsr(relu(x@W1^T+b1))+b2)) @ W3^T + b3
// B=2048, IN=1024, H=2048, OUT=1024, BS=32, RB=CB=64, 32 blocks/row
// Round 9: single-barrier 3-buffer counted-vmcnt pipeline for both GEMMs
// (guide T3 recipe: ONE barrier per K-step, STAGE issued before compute,
// loads get ~2 iterations of slack; WAR-safe because stage target
// (kt+2)%3 == (kt-1)%3 was last read at step kt-1, all waves past it).
// L1 128x64 PIPE3 (72KB, 2/CU); L3 64x64 split-K2 PIPE3 (48KB, 3/CU);
// BSR kept at R8 structure (4/CU). cvt4/combine2 at BW floor.
// ---------------------------------------------------------------------------

typedef __attribute__((ext_vector_type(8))) short bf16x8;
typedef __attribute__((ext_vector_type(4))) float f32x4;

__device__ __forceinline__ unsigned short f2bf(float f) {
    union { float f; unsigned int u; } c; c.f = f;
    unsigned int u = c.u;
    u += 0x7fffu + ((u >> 16) & 1u);   // round-to-nearest-even
    return (unsigned short)(u >> 16);
}

__device__ __forceinline__ void async16(const void* g, void* l) {
    __builtin_amdgcn_global_load_lds(
        (const __attribute__((address_space(1))) void*)g,
        (__attribute__((address_space(3))) void*)l,
        16, 0, 0);
}

template<int N>
__device__ __forceinline__ void vm_wait() {
    asm volatile("s_waitcnt vmcnt(%0)" :: "n"(N) : "memory");
}
__device__ __forceinline__ void barrier() {
    asm volatile("" ::: "memory");
    __builtin_amdgcn_s_barrier();
    asm volatile("" ::: "memory");
}

// ---------------------------------------------------------------------------
// fused f32 -> bf16 conversion of all 4 inputs (each exactly 2^21 elems)
// ---------------------------------------------------------------------------
__global__ __launch_bounds__(256) void cvt4(
    const float* __restrict__ x,  const float* __restrict__ w1,
    const float* __restrict__ w3, const float* __restrict__ v,
    unsigned short* __restrict__ xb,  unsigned short* __restrict__ w1b,
    unsigned short* __restrict__ w3b, unsigned short* __restrict__ vb)
{
    const int NE = 1 << 21;
    int e = (blockIdx.x * 256 + threadIdx.x) * 4;
    int a = e >> 21;                 // uniform within a block
    int off = e & (NE - 1);
    const float* src = (a == 0) ? x : (a == 1) ? w1 : (a == 2) ? w3 : v;
    unsigned short* dst = (a == 0) ? xb : (a == 1) ? w1b : (a == 2) ? w3b : vb;
    float4 vv = *reinterpret_cast<const float4*>(src + off);
    ushort4 o;
    o.x = f2bf(vv.x); o.y = f2bf(vv.y); o.z = f2bf(vv.z); o.w = f2bf(vv.w);
    *reinterpret_cast<ushort4*>(dst + off) = o;
}

// ---------------------------------------------------------------------------
// combine split-K partials: out = p0 + p1 + b3[col]   (2M elems, N=1024)
// ---------------------------------------------------------------------------
__global__ __launch_bounds__(256) void combine2(
    const float* __restrict__ p0, const float* __restrict__ p1,
    const float* __restrict__ b3, float* __restrict__ out)
{
    int i = (blockIdx.x * 256 + threadIdx.x) * 4;
    float4 a = *reinterpret_cast<const float4*>(p0 + i);
    float4 b = *reinterpret_cast<const float4*>(p1 + i);
    float4 c = *reinterpret_cast<const float4*>(b3 + (i & 1023));
    float4 o = {a.x + b.x + c.x, a.y + b.y + c.y,
                a.z + b.z + c.z, a.w + b.w + c.w};
    *reinterpret_cast<float4*>(out + i) = o;
}

// ---------------------------------------------------------------------------
// bf16 GEMM, B^T form: C[M,N] = A[M,K] x B[N,K]^T (+ bias, relu).
// BM x BN tile, BK=64, 256 threads = 4 waves (2x2), THREE LDS buffers,
// single-barrier counted-vmcnt pipeline:
//   iter kt: wait(buf kt done) -> barrier -> STAGE(kt+2) -> compute(kt)
// XOR swizzle chunk^(row&7) on staging-source + ds_read.
// 1-D grid, XCD-pinned decode; KSPLIT=2 decodes ks from blockIdx and writes
// f32 partials (no bias) to C0/C1. OUTMODE: 1 = bf16+bias, 2 = f32 partial.
// ---------------------------------------------------------------------------
template<int BM, int BN, int MCL, int KSPLIT, int RELU, int OUTMODE>
__global__ __launch_bounds__(256) void gemm_bt(
    const unsigned short* __restrict__ A,
    const unsigned short* __restrict__ B,
    const float* __restrict__ bias,
    void* __restrict__ C0,
    void* __restrict__ C1,
    int M, int N, int K)
{
    constexpr int BK = 64;                 // elems; 128B per row
    constexpr int MR = BM / 32;            // MFMA frag repeats per wave
    constexpr int NR = BN / 32;
    constexpr int AI = BM / 32;            // staging instrs per thread (A)
    constexpr int BI = BN / 32;
    constexpr int LPS = AI + BI;           // loads per thread per stage
    __shared__ unsigned short As[3][BM * BK];
    __shared__ unsigned short Bs[3][BN * BK];

    const int t = threadIdx.x;
    const int w = t >> 6;
    const int l = t & 63;

    // XCD-pinned tile decode (+ optional K-split)
    const int id = blockIdx.x;
    const int xcd = id & 7;
    int j = id >> 3;
    int ks = 0;
    if (KSPLIT == 2) { ks = j & 1; j >>= 1; }
    const int mt = xcd * MCL + (j & (MCL - 1));
    const int nt = j / MCL;
    const int bm = mt * BM;
    const int bn = nt * BN;
    const int kb = ks * (K / KSPLIT);

    const int wm = (w >> 1) * (BM / 2);
    const int wn = (w & 1) * (BN / 2);

    f32x4 acc[MR][NR];
    #pragma unroll
    for (int i = 0; i < MR; ++i)
        #pragma unroll
        for (int jj = 0; jj < NR; ++jj)
            acc[i][jj] = (f32x4){0.f, 0.f, 0.f, 0.f};

    // staging: instr i of wave w covers tile rows w*(BM/4)+i*8 + (l>>3);
    // lane chunk (l&7); swizzled source chunk = (l&7) ^ (row&7), row&7==l>>3
    const int arow = bm + w * (BM / 4) + (l >> 3);
    const int brow = bn + w * (BN / 4) + (l >> 3);
    const int scol = ((l & 7) ^ (l >> 3)) * 8;   // elems

    const int fr = l & 15;       // fragment row (within 16)
    const int kg = l >> 4;       // k-group
    const int fq = l >> 4;

    auto stage = [&](int buf, int kt) {
        const int k0 = kb + kt * BK;
        #pragma unroll
        for (int i = 0; i < AI; ++i)
            async16(A + (size_t)(arow + i * 8) * K + k0 + scol,
                    &As[buf][(w * (BM / 4) + i * 8) * BK]);
        #pragma unroll
        for (int i = 0; i < BI; ++i)
            async16(B + (size_t)(brow + i * 8) * K + k0 + scol,
                    &Bs[buf][(w * (BN / 4) + i * 8) * BK]);
    };

    auto compute = [&](int buf) {
        #pragma unroll
        for (int kk = 0; kk < 2; ++kk) {
            const int pc = ((kk * 4 + kg) ^ (fr & 7)) * 8;  // swizzled chunk
            bf16x8 af[MR], bg[NR];
            #pragma unroll
            for (int i = 0; i < MR; ++i)
                af[i] = *reinterpret_cast<const bf16x8*>(
                    &As[buf][(wm + i * 16 + fr) * BK + pc]);
            #pragma unroll
            for (int jj = 0; jj < NR; ++jj)
                bg[jj] = *reinterpret_cast<const bf16x8*>(
                    &Bs[buf][(wn + jj * 16 + fr) * BK + pc]);
            #pragma unroll
            for (int i = 0; i < MR; ++i)
                #pragma unroll
                for (int jj = 0; jj < NR; ++jj)
                    acc[i][jj] = __builtin_amdgcn_mfma_f32_16x16x32_bf16(
                        af[i], bg[jj], acc[i][jj], 0, 0, 0);
        }
    };

    const int nK = (K / KSPLIT) >> 6;      // 16 for all layers here
    stage(0, 0);
    stage(1, 1);
    int cur = 0;                           // kt % 3
    int nxt = 2;                           // (kt+2) % 3
    for (int kt = 0; kt < nK; ++kt) {
        if (kt + 1 < nK) vm_wait<LPS>();   // drain buf[cur]'s loads (FIFO)
        else             vm_wait<0>();
        barrier();                         // all waves: buf[cur] ready,
                                           // buf[nxt] (= last computed) free
        if (kt + 2 < nK) stage(nxt, kt + 2);  // ~2 iterations of slack
        compute(cur);
        cur = (cur == 2) ? 0 : cur + 1;
        nxt = (nxt == 2) ? 0 : nxt + 1;
    }

    // epilogue: C/D layout col = l&15, row = (l>>4)*4 + v
    #pragma unroll
    for (int i = 0; i < MR; ++i) {
        const int row0 = bm + wm + i * 16 + fq * 4;
        #pragma unroll
        for (int jj = 0; jj < NR; ++jj) {
            const int col = bn + wn + jj * 16 + fr;
            const float bv = (OUTMODE == 2) ? 0.f : bias[col];
            #pragma unroll
            for (int v = 0; v < 4; ++v) {
                float r = acc[i][jj][v] + bv;
                if (RELU) r = fmaxf(r, 0.f);
                const size_t off = (size_t)(row0 + v) * N + col;
                if (OUTMODE == 1)
                    ((unsigned short*)C0)[off] = f2bf(r);
                else
                    ((float*)(ks ? C1 : C0))[off] = r;
            }
        }
    }
}

// ---------------------------------------------------------------------------
// BSR layer: 2 nnz blocks per K-step (K-concat), counted-vmcnt pipeline.
// 1-D grid 1024 (4 blocks/CU), XCD-pinned: xcd owns batch-tiles {2x, 2x+1}.
// LDS rows 128B, XOR-swizzled. Wave w owns batch rows w*32..+31 (2x2 frags).
// (R8 structure kept verbatim — not the dominant cost.)
// ---------------------------------------------------------------------------
__global__ __launch_bounds__(256) void bsr_layer(
    const unsigned short* __restrict__ h,     // 2048 x 2048 bf16
    const int* __restrict__ crow,
    const int* __restrict__ cols,
    const unsigned short* __restrict__ vals,  // nnz x 32 x 32 bf16
    const float* __restrict__ b2,
    unsigned short* __restrict__ h2)          // 2048 x 2048 bf16
{
    __shared__ unsigned short Hs[2][128 * 64];
    __shared__ unsigned short Vs[2][32 * 64];
    __shared__ int colsS[64];
    const int t = threadIdx.x;
    const int w = t >> 6;
    const int l = t & 63;

    const int id = blockIdx.x;
    const int xcd = id & 7;
    const int j2 = id >> 3;
    const int bt = xcd * 2 + (j2 & 1);
    const int r  = j2 >> 1;
    const int bm = bt * 128;

    const int s = crow[r];
    const int cnt = crow[r + 1] - s;
    const int wrow = w * 32;

    if (t < cnt) colsS[t] = cols[s + t];

    f32x4 acc[2][2];
    #pragma unroll
    for (int i = 0; i < 2; ++i)
        #pragma unroll
        for (int jj = 0; jj < 2; ++jj)
            acc[i][jj] = (f32x4){0.f, 0.f, 0.f, 0.f};

    const int fr = l & 15;
    const int kg = l >> 4;
    const int lr = l >> 3;               // staging row-in-group
    const int sc = (l & 7) ^ lr;         // swizzled source chunk

    auto stage = [&](int buf, int js) {
        const int n0 = s + 2 * js;
        const bool tail = (2 * js + 1 >= cnt);
        const int c0 = colsS[2 * js];
        const int c1 = tail ? c0 : colsS[2 * js + 1];
        const int n1 = tail ? n0 : n0 + 1;
        #pragma unroll
        for (int i = 0; i < 4; ++i) {
            const int row = bm + w * 32 + i * 8 + lr;
            const int col = (sc & 4) ? c1 * 32 + (sc & 3) * 8 : c0 * 32 + sc * 8;
            async16(h + (size_t)row * 2048 + col,
                    &Hs[buf][(w * 32 + i * 8) * 64]);
        }
        const int vrow = w * 8 + lr;
        if (!tail || !(sc & 4)) {
            const unsigned short* src =
                vals + (size_t)((sc & 4) ? n1 : n0) * 1024 + vrow * 32 + (sc & 3) * 8;
            async16(src, &Vs[buf][(w * 8) * 64]);
        } else {
            bf16x8 z = (bf16x8){0,0,0,0,0,0,0,0};
            *reinterpret_cast<bf16x8*>(&Vs[buf][vrow * 64 + (l & 7) * 8]) = z;
        }
    };

    auto compute = [&](int buf) {
        #pragma unroll
        for (int kk = 0; kk < 2; ++kk) {
            const int pc = ((kk * 4 + kg) ^ (fr & 7)) * 8;
            bf16x8 af[2], bg[2];
            #pragma unroll
            for (int i = 0; i < 2; ++i)
                af[i] = *reinterpret_cast<const bf16x8*>(
                    &Hs[buf][(wrow + i * 16 + fr) * 64 + pc]);
            #pragma unroll
            for (int jj = 0; jj < 2; ++jj)
                bg[jj] = *reinterpret_cast<const bf16x8*>(
                    &Vs[buf][(jj * 16 + fr) * 64 + pc]);
            #pragma unroll
            for (int i = 0; i < 2; ++i)
                #pragma unroll
                for (int jj = 0; jj < 2; ++jj)
                    acc[i][jj] = __builtin_amdgcn_mfma_f32_16x16x32_bf16(
                        af[i], bg[jj], acc[i][jj], 0, 0, 0);
        }
    };

    __syncthreads();               // colsS visible; pipeline starts clean
    const int nsteps = (cnt + 1) >> 1;
    stage(0, 0);
    if (nsteps > 1) stage(1, 1);
    int cur = 0;
    for (int js = 0; js < nsteps - 1; ++js) {
        vm_wait<5>();
        barrier();
        compute(cur);
        barrier();
        if (js + 2 < nsteps) stage(cur, js + 2);
        cur ^= 1;
    }
    vm_wait<0>();
    barrier();
    compute(cur);

    const int fq = l >> 4;
    #pragma unroll
    for (int i = 0; i < 2; ++i) {
        const int row0 = bm + wrow + i * 16 + fq * 4;
        #pragma unroll
        for (int jj = 0; jj < 2; ++jj) {
            const int col = r * 32 + jj * 16 + fr;
            const float bv = b2[col];
            #pragma unroll
            for (int v = 0; v < 4; ++v) {
                float rv = fmaxf(acc[i][jj][v] + bv, 0.f);
                h2[(size_t)(row0 + v) * 2048 + col] = f2bf(rv);
            }
        }
    }
}

// ---------------------------------------------------------------------------
extern "C" void kernel_launch(void* const* d_in, const int* in_sizes, int n_in,
                              void* d_out, int out_size, void* d_ws, size_t ws_size,
                              hipStream_t stream) {
    const float* x    = (const float*)d_in[0];   // 2048x1024
    const float* W1   = (const float*)d_in[1];   // 2048x1024
    const float* b1   = (const float*)d_in[2];   // 2048
    const int*   crow = (const int*)d_in[3];     // 65
    const int*   cols = (const int*)d_in[4];     // 2048
    const float* vals = (const float*)d_in[5];   // 2048x32x32
    const float* b2   = (const float*)d_in[6];   // 2048
    const float* W3   = (const float*)d_in[7];   // 1024x2048
    const float* b3   = (const float*)d_in[8];   // 1024
    float* out = (float*)d_out;                  // 2048x1024 f32

    const int NE = 2 * 1024 * 1024;
    unsigned short* xb  = (unsigned short*)d_ws;         // [0,  4MB)
    unsigned short* w1b = xb  + NE;                      // [4,  8MB)
    unsigned short* w3b = w1b + NE;                      // [8, 12MB)
    unsigned short* vb  = w3b + NE;                      // [12,16MB)
    unsigned short* hb  = vb  + NE;                      // [16,24MB)
    unsigned short* h2b = hb  + 2 * NE;                  // [24,32MB)
    // split-K partials overlay regions dead by L3-time:
    float* p0 = (float*)d_ws;        // [0, 8MB)  over xb+w1b (dead after L1)
    float* p1 = (float*)hb;          // [16,24MB) over hb     (dead after BSR)

    cvt4<<<8192, 256, 0, stream>>>(x, W1, W3, vals, xb, w1b, w3b, vb);

    // L1: h = relu(x @ W1^T + b1)  M=2048 N=2048 K=1024, tile 128x64,
    // grid 512 (2 blocks/CU), 3 LDS buffers (72KB), single-barrier loop
    gemm_bt<128, 64, 2, 1, 1, 1><<<512, 256, 0, stream>>>(
        xb, w1b, b1, hb, nullptr, 2048, 2048, 1024);
    // L2: BSR + relu, grid 1024 (4 blocks/CU)
    bsr_layer<<<1024, 256, 0, stream>>>(hb, crow, cols, vb, b2, h2b);
    // L3: tile 64x64, split-K2 in ONE 1024-block launch (48KB, 3/CU,
    // 16 K-steps each), f32 partials -> p0/p1, single-barrier loop
    gemm_bt<64, 64, 4, 2, 0, 2><<<1024, 256, 0, stream>>>(
        h2b, w3b, nullptr, p0, p1, 2048, 1024, 2048);
    // combine: out = p0 + p1 + b3
    combine2<<<2048, 256, 0, stream>>>(p0, p1, b3, out);

    (void)in_sizes; (void)n_in; (void)out_size; (void)ws_size;
}

// Round 10
// 82.786 us; speedup vs baseline: 1.0450x; 1.0450x over previous
//
#include <hip/hip_runtime.h>
#include <hip/hip_bf16.h>

// ---------------------------------------------------------------------------
// BlockedMLP: out = (relu(bsr(relu(x@W1^T+b1))+b2)) @ W3^T + b3
// B=2048, IN=1024, H=2048, OUT=1024, BS=32, RB=CB=64, 32 blocks/row
// Round 10: arithmetic-intensity push. Both GEMMs: 128x128 tile, 512 thr
// (8 waves 2Mx4N, each 64x32), PIPE=3, R8's two-barrier counted-vmcnt.
// 64 MAC/staged-elem makes each K-step compute-bound (621cyc MFMA vs
// 585cyc L2 load); PIPE3 gives loads ~2 iterations of slack.
// L3 = split-K2 (grid 256) -> f32 partials -> combine2. BSR/cvt R8-exact.
// R9 post-mortem: single-barrier + L3 48KB (4->3 blocks/CU) regressed;
// reverted to two-barrier everywhere.
// ---------------------------------------------------------------------------

typedef __attribute__((ext_vector_type(8))) short bf16x8;
typedef __attribute__((ext_vector_type(4))) float f32x4;

__device__ __forceinline__ unsigned short f2bf(float f) {
    union { float f; unsigned int u; } c; c.f = f;
    unsigned int u = c.u;
    u += 0x7fffu + ((u >> 16) & 1u);   // round-to-nearest-even
    return (unsigned short)(u >> 16);
}

__device__ __forceinline__ void async16(const void* g, void* l) {
    __builtin_amdgcn_global_load_lds(
        (const __attribute__((address_space(1))) void*)g,
        (__attribute__((address_space(3))) void*)l,
        16, 0, 0);
}

template<int N>
__device__ __forceinline__ void vm_wait() {
    asm volatile("s_waitcnt vmcnt(%0)" :: "n"(N) : "memory");
}
__device__ __forceinline__ void barrier() {
    asm volatile("" ::: "memory");
    __builtin_amdgcn_s_barrier();
    asm volatile("" ::: "memory");
}

// ---------------------------------------------------------------------------
// fused f32 -> bf16 conversion of all 4 inputs (each exactly 2^21 elems)
// ---------------------------------------------------------------------------
__global__ __launch_bounds__(256) void cvt4(
    const float* __restrict__ x,  const float* __restrict__ w1,
    const float* __restrict__ w3, const float* __restrict__ v,
    unsigned short* __restrict__ xb,  unsigned short* __restrict__ w1b,
    unsigned short* __restrict__ w3b, unsigned short* __restrict__ vb)
{
    const int NE = 1 << 21;
    int e = (blockIdx.x * 256 + threadIdx.x) * 4;
    int a = e >> 21;                 // uniform within a block
    int off = e & (NE - 1);
    const float* src = (a == 0) ? x : (a == 1) ? w1 : (a == 2) ? w3 : v;
    unsigned short* dst = (a == 0) ? xb : (a == 1) ? w1b : (a == 2) ? w3b : vb;
    float4 vv = *reinterpret_cast<const float4*>(src + off);
    ushort4 o;
    o.x = f2bf(vv.x); o.y = f2bf(vv.y); o.z = f2bf(vv.z); o.w = f2bf(vv.w);
    *reinterpret_cast<ushort4*>(dst + off) = o;
}

// ---------------------------------------------------------------------------
// combine split-K partials: out = p0 + p1 + b3[col]   (2M elems, N=1024)
// ---------------------------------------------------------------------------
__global__ __launch_bounds__(256) void combine2(
    const float* __restrict__ p0, const float* __restrict__ p1,
    const float* __restrict__ b3, float* __restrict__ out)
{
    int i = (blockIdx.x * 256 + threadIdx.x) * 4;
    float4 a = *reinterpret_cast<const float4*>(p0 + i);
    float4 b = *reinterpret_cast<const float4*>(p1 + i);
    float4 c = *reinterpret_cast<const float4*>(b3 + (i & 1023));
    float4 o = {a.x + b.x + c.x, a.y + b.y + c.y,
                a.z + b.z + c.z, a.w + b.w + c.w};
    *reinterpret_cast<float4*>(out + i) = o;
}

// ---------------------------------------------------------------------------
// bf16 GEMM, B^T form, 128x128 tile, 512 threads = 8 waves (2M x 4N),
// each wave 64x32 (4x2 frags of 16x16x32). THREE LDS buffers (96KB),
// two-barrier counted-vmcnt pipeline (loads span 2 iterations):
//   prologue: stage(0),stage(1),stage(2)
//   iter kt : wait(8/4/0) -> barrier -> compute(kt) -> barrier -> stage(kt+3)
// XOR swizzle chunk^(row&7) on staging source + ds_read (BK=64, 128B rows).
// 1-D grid, XCD-pinned; KSPLIT=2 decodes ks and writes f32 partials to C0/C1.
// OUTMODE: 1 = bf16 + bias(+relu), 2 = f32 partial (no bias).
// ---------------------------------------------------------------------------
template<int MCL, int KSPLIT, int RELU, int OUTMODE>
__global__ __launch_bounds__(512) void gemm8(
    const unsigned short* __restrict__ A,
    const unsigned short* __restrict__ B,
    const float* __restrict__ bias,
    void* __restrict__ C0,
    void* __restrict__ C1,
    int M, int N, int K)
{
    constexpr int BM = 128, BN = 128, BK = 64;
    constexpr int LPS = 4;                 // 2 A + 2 B loads per thread/stage
    __shared__ unsigned short As[3][BM * BK];
    __shared__ unsigned short Bs[3][BN * BK];

    const int t = threadIdx.x;
    const int w = t >> 6;                  // 0..7
    const int l = t & 63;

    // XCD-pinned tile decode (+ optional K-split)
    const int id = blockIdx.x;
    const int xcd = id & 7;
    int j = id >> 3;
    int ks = 0;
    if (KSPLIT == 2) { ks = j & 1; j >>= 1; }
    const int mt = xcd * MCL + (j & (MCL - 1));
    const int nt = j / MCL;
    const int bm = mt * BM;
    const int bn = nt * BN;
    const int kb = ks * (K / KSPLIT);

    const int wm = (w >> 2) * 64;          // wave row offset (2 in M)
    const int wn = (w & 3) * 32;           // wave col offset (4 in N)

    f32x4 acc[4][2];
    #pragma unroll
    for (int i = 0; i < 4; ++i)
        #pragma unroll
        for (int jj = 0; jj < 2; ++jj)
            acc[i][jj] = (f32x4){0.f, 0.f, 0.f, 0.f};

    // staging: instr i covers rows i*64 + w*8 + (l>>3); chunk (l&7);
    // swizzled source chunk = (l&7) ^ (row&7), row&7 == l>>3 here.
    const int r8 = l >> 3;
    const int scol = ((l & 7) ^ r8) * 8;   // elems

    const int fr = l & 15;                 // fragment row
    const int kg = l >> 4;                 // k-group (0..3)
    const int fq = l >> 4;

    auto stage = [&](int buf, int kt) {
        const int k0 = kb + kt * BK;
        #pragma unroll
        for (int i = 0; i < 2; ++i)
            async16(A + (size_t)(bm + i * 64 + w * 8 + r8) * K + k0 + scol,
                    &As[buf][(i * 64 + w * 8) * BK]);
        #pragma unroll
        for (int i = 0; i < 2; ++i)
            async16(B + (size_t)(bn + i * 64 + w * 8 + r8) * K + k0 + scol,
                    &Bs[buf][(i * 64 + w * 8) * BK]);
    };

    auto compute = [&](int buf) {
        #pragma unroll
        for (int kk = 0; kk < 2; ++kk) {
            const int pc = ((kk * 4 + kg) ^ (fr & 7)) * 8;  // swizzled chunk
            bf16x8 af[4], bg[2];
            #pragma unroll
            for (int i = 0; i < 4; ++i)
                af[i] = *reinterpret_cast<const bf16x8*>(
                    &As[buf][(wm + i * 16 + fr) * BK + pc]);
            #pragma unroll
            for (int jj = 0; jj < 2; ++jj)
                bg[jj] = *reinterpret_cast<const bf16x8*>(
                    &Bs[buf][(wn + jj * 16 + fr) * BK + pc]);
            #pragma unroll
            for (int i = 0; i < 4; ++i)
                #pragma unroll
                for (int jj = 0; jj < 2; ++jj)
                    acc[i][jj] = __builtin_amdgcn_mfma_f32_16x16x32_bf16(
                        af[i], bg[jj], acc[i][jj], 0, 0, 0);
        }
    };

    const int nK = (K / KSPLIT) >> 6;      // 16 for all layers here
    stage(0, 0);
    stage(1, 1);
    stage(2, 2);
    int cur = 0;
    for (int kt = 0; kt < nK; ++kt) {
        if (kt < nK - 2)       vm_wait<2 * LPS>();
        else if (kt == nK - 2) vm_wait<LPS>();
        else                   vm_wait<0>();
        barrier();                         // all waves: buf[cur] loads landed
        compute(cur);
        if (kt + 3 < nK) {
            barrier();                     // WAR: all waves done with buf[cur]
            stage(cur, kt + 3);            // loads get ~2 iterations of slack
        } else if (kt + 1 < nK) {
            barrier();
        }
        cur = (cur == 2) ? 0 : cur + 1;
    }

    // epilogue: C/D layout col = l&15, row = (l>>4)*4 + v
    #pragma unroll
    for (int i = 0; i < 4; ++i) {
        const int row0 = bm + wm + i * 16 + fq * 4;
        #pragma unroll
        for (int jj = 0; jj < 2; ++jj) {
            const int col = bn + wn + jj * 16 + fr;
            const float bv = (OUTMODE == 2) ? 0.f : bias[col];
            #pragma unroll
            for (int v = 0; v < 4; ++v) {
                float r = acc[i][jj][v] + bv;
                if (RELU) r = fmaxf(r, 0.f);
                const size_t off = (size_t)(row0 + v) * N + col;
                if (OUTMODE == 1)
                    ((unsigned short*)C0)[off] = f2bf(r);
                else
                    ((float*)(ks ? C1 : C0))[off] = r;
            }
        }
    }
}

// ---------------------------------------------------------------------------
// BSR layer: 2 nnz blocks per K-step (K-concat), counted-vmcnt pipeline.
// 1-D grid 1024 (4 blocks/CU), XCD-pinned. R8-exact.
// ---------------------------------------------------------------------------
__global__ __launch_bounds__(256) void bsr_layer(
    const unsigned short* __restrict__ h,     // 2048 x 2048 bf16
    const int* __restrict__ crow,
    const int* __restrict__ cols,
    const unsigned short* __restrict__ vals,  // nnz x 32 x 32 bf16
    const float* __restrict__ b2,
    unsigned short* __restrict__ h2)          // 2048 x 2048 bf16
{
    __shared__ unsigned short Hs[2][128 * 64];
    __shared__ unsigned short Vs[2][32 * 64];
    __shared__ int colsS[64];
    const int t = threadIdx.x;
    const int w = t >> 6;
    const int l = t & 63;

    const int id = blockIdx.x;
    const int xcd = id & 7;
    const int j2 = id >> 3;
    const int bt = xcd * 2 + (j2 & 1);
    const int r  = j2 >> 1;
    const int bm = bt * 128;

    const int s = crow[r];
    const int cnt = crow[r + 1] - s;
    const int wrow = w * 32;

    if (t < cnt) colsS[t] = cols[s + t];

    f32x4 acc[2][2];
    #pragma unroll
    for (int i = 0; i < 2; ++i)
        #pragma unroll
        for (int jj = 0; jj < 2; ++jj)
            acc[i][jj] = (f32x4){0.f, 0.f, 0.f, 0.f};

    const int fr = l & 15;
    const int kg = l >> 4;
    const int lr = l >> 3;               // staging row-in-group
    const int sc = (l & 7) ^ lr;         // swizzled source chunk

    auto stage = [&](int buf, int js) {
        const int n0 = s + 2 * js;
        const bool tail = (2 * js + 1 >= cnt);
        const int c0 = colsS[2 * js];
        const int c1 = tail ? c0 : colsS[2 * js + 1];
        const int n1 = tail ? n0 : n0 + 1;
        #pragma unroll
        for (int i = 0; i < 4; ++i) {
            const int row = bm + w * 32 + i * 8 + lr;
            const int col = (sc & 4) ? c1 * 32 + (sc & 3) * 8 : c0 * 32 + sc * 8;
            async16(h + (size_t)row * 2048 + col,
                    &Hs[buf][(w * 32 + i * 8) * 64]);
        }
        const int vrow = w * 8 + lr;
        if (!tail || !(sc & 4)) {
            const unsigned short* src =
                vals + (size_t)((sc & 4) ? n1 : n0) * 1024 + vrow * 32 + (sc & 3) * 8;
            async16(src, &Vs[buf][(w * 8) * 64]);
        } else {
            bf16x8 z = (bf16x8){0,0,0,0,0,0,0,0};
            *reinterpret_cast<bf16x8*>(&Vs[buf][vrow * 64 + (l & 7) * 8]) = z;
        }
    };

    auto compute = [&](int buf) {
        #pragma unroll
        for (int kk = 0; kk < 2; ++kk) {
            const int pc = ((kk * 4 + kg) ^ (fr & 7)) * 8;
            bf16x8 af[2], bg[2];
            #pragma unroll
            for (int i = 0; i < 2; ++i)
                af[i] = *reinterpret_cast<const bf16x8*>(
                    &Hs[buf][(wrow + i * 16 + fr) * 64 + pc]);
            #pragma unroll
            for (int jj = 0; jj < 2; ++jj)
                bg[jj] = *reinterpret_cast<const bf16x8*>(
                    &Vs[buf][(jj * 16 + fr) * 64 + pc]);
            #pragma unroll
            for (int i = 0; i < 2; ++i)
                #pragma unroll
                for (int jj = 0; jj < 2; ++jj)
                    acc[i][jj] = __builtin_amdgcn_mfma_f32_16x16x32_bf16(
                        af[i], bg[jj], acc[i][jj], 0, 0, 0);
        }
    };

    __syncthreads();               // colsS visible; pipeline starts clean
    const int nsteps = (cnt + 1) >> 1;
    stage(0, 0);
    if (nsteps > 1) stage(1, 1);
    int cur = 0;
    for (int js = 0; js < nsteps - 1; ++js) {
        vm_wait<5>();
        barrier();
        compute(cur);
        barrier();
        if (js + 2 < nsteps) stage(cur, js + 2);
        cur ^= 1;
    }
    vm_wait<0>();
    barrier();
    compute(cur);

    const int fq = l >> 4;
    #pragma unroll
    for (int i = 0; i < 2; ++i) {
        const int row0 = bm + wrow + i * 16 + fq * 4;
        #pragma unroll
        for (int jj = 0; jj < 2; ++jj) {
            const int col = r * 32 + jj * 16 + fr;
            const float bv = b2[col];
            #pragma unroll
            for (int v = 0; v < 4; ++v) {
                float rv = fmaxf(acc[i][jj][v] + bv, 0.f);
                h2[(size_t)(row0 + v) * 2048 + col] = f2bf(rv);
            }
        }
    }
}

// ---------------------------------------------------------------------------
extern "C" void kernel_launch(void* const* d_in, const int* in_sizes, int n_in,
                              void* d_out, int out_size, void* d_ws, size_t ws_size,
                              hipStream_t stream) {
    const float* x    = (const float*)d_in[0];   // 2048x1024
    const float* W1   = (const float*)d_in[1];   // 2048x1024
    const float* b1   = (const float*)d_in[2];   // 2048
    const int*   crow = (const int*)d_in[3];     // 65
    const int*   cols = (const int*)d_in[4];     // 2048
    const float* vals = (const float*)d_in[5];   // 2048x32x32
    const float* b2   = (const float*)d_in[6];   // 2048
    const float* W3   = (const float*)d_in[7];   // 1024x2048
    const float* b3   = (const float*)d_in[8];   // 1024
    float* out = (float*)d_out;                  // 2048x1024 f32

    const int NE = 2 * 1024 * 1024;
    unsigned short* xb  = (unsigned short*)d_ws;         // [0,  4MB)
    unsigned short* w1b = xb  + NE;                      // [4,  8MB)
    unsigned short* w3b = w1b + NE;                      // [8, 12MB)
    unsigned short* vb  = w3b + NE;                      // [12,16MB)
    unsigned short* hb  = vb  + NE;                      // [16,24MB)
    unsigned short* h2b = hb  + 2 * NE;                  // [24,32MB)
    // split-K partials overlay regions dead by L3-time:
    float* p0 = (float*)d_ws;        // [0, 8MB)  over xb+w1b (dead after L1)
    float* p1 = (float*)hb;          // [16,24MB) over hb     (dead after BSR)

    cvt4<<<8192, 256, 0, stream>>>(x, W1, W3, vals, xb, w1b, w3b, vb);

    // L1: h = relu(x @ W1^T + b1)  M=2048 N=2048 K=1024, tile 128x128,
    // 512 thr, PIPE3, grid 16x16 = 256 blocks (1/CU, 8 waves/CU)
    gemm8<2, 1, 1, 1><<<256, 512, 0, stream>>>(
        xb, w1b, b1, hb, nullptr, 2048, 2048, 1024);
    // L2: BSR + relu, grid 1024 (4 blocks/CU) — R8-exact
    bsr_layer<<<1024, 256, 0, stream>>>(hb, crow, cols, vb, b2, h2b);
    // L3: tile 128x128, split-K2, 512 thr, PIPE3, grid 16x8x2 = 256 blocks,
    // f32 partials -> p0/p1
    gemm8<2, 2, 0, 2><<<256, 512, 0, stream>>>(
        h2b, w3b, nullptr, p0, p1, 2048, 1024, 2048);
    // combine: out = p0 + p1 + b3
    combine2<<<2048, 256, 0, stream>>>(p0, p1, b3, out);

    (void)in_sizes; (void)n_in; (void)out_size; (void)ws_size;
}

// Round 11
// 76.983 us; speedup vs baseline: 1.1238x; 1.0754x over previous
//
#include <hip/hip_runtime.h>
#include <hip/hip_bf16.h>

// ---------------------------------------------------------------------------
// BlockedMLP: out = (relu(bsr(relu(x@W1^T+b1))+b2)) @ W3^T + b3
// B=2048, IN=1024, H=2048, OUT=1024, BS=32, RB=CB=64, 32 blocks/row
// Round 11: R8 base (best, 77.8us). Single delta: L3 = 64x32 tile, grid
// 1024 (4 blocks/CU) WITHOUT split-K -> no combine kernel, no partial
// traffic, one fewer kernel boundary. Same intensity (42.7 MAC/elem) as
// the proven 128x64; occupancy is the lever with consistent sign (R3/R6).
// R10 post-mortem: 128x128 @ 1 block/CU regressed (no cross-block TLP).
// ---------------------------------------------------------------------------

typedef __attribute__((ext_vector_type(8))) short bf16x8;
typedef __attribute__((ext_vector_type(4))) float f32x4;

__device__ __forceinline__ unsigned short f2bf(float f) {
    union { float f; unsigned int u; } c; c.f = f;
    unsigned int u = c.u;
    u += 0x7fffu + ((u >> 16) & 1u);   // round-to-nearest-even
    return (unsigned short)(u >> 16);
}

__device__ __forceinline__ void async16(const void* g, void* l) {
    __builtin_amdgcn_global_load_lds(
        (const __attribute__((address_space(1))) void*)g,
        (__attribute__((address_space(3))) void*)l,
        16, 0, 0);
}

template<int N>
__device__ __forceinline__ void vm_wait() {
    asm volatile("s_waitcnt vmcnt(%0)" :: "n"(N) : "memory");
}
__device__ __forceinline__ void barrier() {
    asm volatile("" ::: "memory");
    __builtin_amdgcn_s_barrier();
    asm volatile("" ::: "memory");
}

// ---------------------------------------------------------------------------
// fused f32 -> bf16 conversion of all 4 inputs (each exactly 2^21 elems)
// ---------------------------------------------------------------------------
__global__ __launch_bounds__(256) void cvt4(
    const float* __restrict__ x,  const float* __restrict__ w1,
    const float* __restrict__ w3, const float* __restrict__ v,
    unsigned short* __restrict__ xb,  unsigned short* __restrict__ w1b,
    unsigned short* __restrict__ w3b, unsigned short* __restrict__ vb)
{
    const int NE = 1 << 21;
    int e = (blockIdx.x * 256 + threadIdx.x) * 4;
    int a = e >> 21;                 // uniform within a block
    int off = e & (NE - 1);
    const float* src = (a == 0) ? x : (a == 1) ? w1 : (a == 2) ? w3 : v;
    unsigned short* dst = (a == 0) ? xb : (a == 1) ? w1b : (a == 2) ? w3b : vb;
    float4 vv = *reinterpret_cast<const float4*>(src + off);
    ushort4 o;
    o.x = f2bf(vv.x); o.y = f2bf(vv.y); o.z = f2bf(vv.z); o.w = f2bf(vv.w);
    *reinterpret_cast<ushort4*>(dst + off) = o;
}

// ---------------------------------------------------------------------------
// bf16 GEMM, B^T form: C[M,N] = A[M,K] x B[N,K]^T (+ bias, relu).
// BM x BN tile, BK=64, 256 threads = 4 waves (2x2), PIPE-deep LDS buffers,
// counted-vmcnt pipeline (PIPE-1 stages in flight across barriers),
// XOR swizzle chunk^(row&7) on staging-source + ds_read.
// 1-D grid, XCD-pinned decode; KSPLIT=2 decodes ks from blockIdx and writes
// f32 partials (no bias) to C0/C1.
// OUTMODE: 0 = f32+bias, 1 = bf16+bias, 2 = f32 partial (no bias).
// ---------------------------------------------------------------------------
template<int BM, int BN, int MCL, int KSPLIT, int PIPE, int RELU, int OUTMODE>
__global__ __launch_bounds__(256) void gemm_bt(
    const unsigned short* __restrict__ A,
    const unsigned short* __restrict__ B,
    const float* __restrict__ bias,
    void* __restrict__ C0,
    void* __restrict__ C1,
    int M, int N, int K)
{
    constexpr int BK = 64;                 // elems; 128B per row
    constexpr int MR = BM / 32;            // MFMA frag repeats per wave
    constexpr int NR = BN / 32;
    constexpr int AI = BM / 32;            // staging instrs per thread (A)
    constexpr int BI = BN / 32;
    constexpr int LPS = AI + BI;           // loads per thread per stage
    __shared__ unsigned short As[PIPE][BM * BK];
    __shared__ unsigned short Bs[PIPE][BN * BK];

    const int t = threadIdx.x;
    const int w = t >> 6;
    const int l = t & 63;

    // XCD-pinned tile decode (+ optional K-split)
    const int id = blockIdx.x;
    const int xcd = id & 7;
    int j = id >> 3;
    int ks = 0;
    if (KSPLIT == 2) { ks = j & 1; j >>= 1; }
    const int mt = xcd * MCL + (j & (MCL - 1));
    const int nt = j / MCL;
    const int bm = mt * BM;
    const int bn = nt * BN;
    const int kb = ks * (K / KSPLIT);

    const int wm = (w >> 1) * (BM / 2);
    const int wn = (w & 1) * (BN / 2);

    f32x4 acc[MR][NR];
    #pragma unroll
    for (int i = 0; i < MR; ++i)
        #pragma unroll
        for (int jj = 0; jj < NR; ++jj)
            acc[i][jj] = (f32x4){0.f, 0.f, 0.f, 0.f};

    // staging: instr i of wave w covers tile rows w*(BM/4)+i*8 + (l>>3);
    // lane chunk (l&7); swizzled source chunk = (l&7) ^ (row&7), row&7==l>>3
    const int arow = bm + w * (BM / 4) + (l >> 3);
    const int brow = bn + w * (BN / 4) + (l >> 3);
    const int scol = ((l & 7) ^ (l >> 3)) * 8;   // elems

    const int fr = l & 15;       // fragment row (within 16)
    const int kg = l >> 4;       // k-group
    const int fq = l >> 4;

    auto stage = [&](int buf, int kt) {
        const int k0 = kb + kt * BK;
        #pragma unroll
        for (int i = 0; i < AI; ++i)
            async16(A + (size_t)(arow + i * 8) * K + k0 + scol,
                    &As[buf][(w * (BM / 4) + i * 8) * BK]);
        #pragma unroll
        for (int i = 0; i < BI; ++i)
            async16(B + (size_t)(brow + i * 8) * K + k0 + scol,
                    &Bs[buf][(w * (BN / 4) + i * 8) * BK]);
    };

    auto compute = [&](int buf) {
        #pragma unroll
        for (int kk = 0; kk < 2; ++kk) {
            const int pc = ((kk * 4 + kg) ^ (fr & 7)) * 8;  // swizzled chunk
            bf16x8 af[MR], bg[NR];
            #pragma unroll
            for (int i = 0; i < MR; ++i)
                af[i] = *reinterpret_cast<const bf16x8*>(
                    &As[buf][(wm + i * 16 + fr) * BK + pc]);
            #pragma unroll
            for (int jj = 0; jj < NR; ++jj)
                bg[jj] = *reinterpret_cast<const bf16x8*>(
                    &Bs[buf][(wn + jj * 16 + fr) * BK + pc]);
            #pragma unroll
            for (int i = 0; i < MR; ++i)
                #pragma unroll
                for (int jj = 0; jj < NR; ++jj)
                    acc[i][jj] = __builtin_amdgcn_mfma_f32_16x16x32_bf16(
                        af[i], bg[jj], acc[i][jj], 0, 0, 0);
        }
    };

    const int nK = (K / KSPLIT) >> 6;
    stage(0, 0);
    stage(1, 1);
    if (PIPE == 3) stage(2, 2);
    int cur = 0;
    for (int kt = 0; kt < nK; ++kt) {
        if (PIPE == 3) {
            if (kt < nK - 2)       vm_wait<2 * LPS>();
            else if (kt == nK - 2) vm_wait<LPS>();
            else                   vm_wait<0>();
        } else {
            if (kt < nK - 1)       vm_wait<LPS>();
            else                   vm_wait<0>();
        }
        barrier();                 // all waves' buf[cur] loads drained
        compute(cur);
        if (kt + PIPE < nK) {
            barrier();             // WAR: all waves done reading buf[cur]
            stage(cur, kt + PIPE); // these loads span PIPE-1 iterations
        } else if (kt + 1 < nK) {
            barrier();
        }
        cur = (cur == PIPE - 1) ? 0 : cur + 1;
    }

    // epilogue: C/D layout col = l&15, row = (l>>4)*4 + v
    #pragma unroll
    for (int i = 0; i < MR; ++i) {
        const int row0 = bm + wm + i * 16 + fq * 4;
        #pragma unroll
        for (int jj = 0; jj < NR; ++jj) {
            const int col = bn + wn + jj * 16 + fr;
            const float bv = (OUTMODE == 2) ? 0.f : bias[col];
            #pragma unroll
            for (int v = 0; v < 4; ++v) {
                float r = acc[i][jj][v] + bv;
                if (RELU) r = fmaxf(r, 0.f);
                const size_t off = (size_t)(row0 + v) * N + col;
                if (OUTMODE == 1)
                    ((unsigned short*)C0)[off] = f2bf(r);
                else
                    ((float*)(ks ? C1 : C0))[off] = r;
            }
        }
    }
}

// ---------------------------------------------------------------------------
// BSR layer: 2 nnz blocks per K-step (K-concat), counted-vmcnt pipeline.
// 1-D grid 1024 (4 blocks/CU), XCD-pinned: xcd owns batch-tiles {2x, 2x+1}.
// LDS rows 128B, XOR-swizzled. Wave w owns batch rows w*32..+31 (2x2 frags).
// (R8 structure kept verbatim.)
// ---------------------------------------------------------------------------
__global__ __launch_bounds__(256) void bsr_layer(
    const unsigned short* __restrict__ h,     // 2048 x 2048 bf16
    const int* __restrict__ crow,
    const int* __restrict__ cols,
    const unsigned short* __restrict__ vals,  // nnz x 32 x 32 bf16
    const float* __restrict__ b2,
    unsigned short* __restrict__ h2)          // 2048 x 2048 bf16
{
    __shared__ unsigned short Hs[2][128 * 64];
    __shared__ unsigned short Vs[2][32 * 64];
    __shared__ int colsS[64];
    const int t = threadIdx.x;
    const int w = t >> 6;
    const int l = t & 63;

    const int id = blockIdx.x;
    const int xcd = id & 7;
    const int j2 = id >> 3;
    const int bt = xcd * 2 + (j2 & 1);
    const int r  = j2 >> 1;
    const int bm = bt * 128;

    const int s = crow[r];
    const int cnt = crow[r + 1] - s;
    const int wrow = w * 32;

    if (t < cnt) colsS[t] = cols[s + t];

    f32x4 acc[2][2];
    #pragma unroll
    for (int i = 0; i < 2; ++i)
        #pragma unroll
        for (int jj = 0; jj < 2; ++jj)
            acc[i][jj] = (f32x4){0.f, 0.f, 0.f, 0.f};

    const int fr = l & 15;
    const int kg = l >> 4;
    const int lr = l >> 3;               // staging row-in-group
    const int sc = (l & 7) ^ lr;         // swizzled source chunk

    auto stage = [&](int buf, int js) {
        const int n0 = s + 2 * js;
        const bool tail = (2 * js + 1 >= cnt);
        const int c0 = colsS[2 * js];
        const int c1 = tail ? c0 : colsS[2 * js + 1];
        const int n1 = tail ? n0 : n0 + 1;
        #pragma unroll
        for (int i = 0; i < 4; ++i) {
            const int row = bm + w * 32 + i * 8 + lr;
            const int col = (sc & 4) ? c1 * 32 + (sc & 3) * 8 : c0 * 32 + sc * 8;
            async16(h + (size_t)row * 2048 + col,
                    &Hs[buf][(w * 32 + i * 8) * 64]);
        }
        const int vrow = w * 8 + lr;
        if (!tail || !(sc & 4)) {
            const unsigned short* src =
                vals + (size_t)((sc & 4) ? n1 : n0) * 1024 + vrow * 32 + (sc & 3) * 8;
            async16(src, &Vs[buf][(w * 8) * 64]);
        } else {
            bf16x8 z = (bf16x8){0,0,0,0,0,0,0,0};
            *reinterpret_cast<bf16x8*>(&Vs[buf][vrow * 64 + (l & 7) * 8]) = z;
        }
    };

    auto compute = [&](int buf) {
        #pragma unroll
        for (int kk = 0; kk < 2; ++kk) {
            const int pc = ((kk * 4 + kg) ^ (fr & 7)) * 8;
            bf16x8 af[2], bg[2];
            #pragma unroll
            for (int i = 0; i < 2; ++i)
                af[i] = *reinterpret_cast<const bf16x8*>(
                    &Hs[buf][(wrow + i * 16 + fr) * 64 + pc]);
            #pragma unroll
            for (int jj = 0; jj < 2; ++jj)
                bg[jj] = *reinterpret_cast<const bf16x8*>(
                    &Vs[buf][(jj * 16 + fr) * 64 + pc]);
            #pragma unroll
            for (int i = 0; i < 2; ++i)
                #pragma unroll
                for (int jj = 0; jj < 2; ++jj)
                    acc[i][jj] = __builtin_amdgcn_mfma_f32_16x16x32_bf16(
                        af[i], bg[jj], acc[i][jj], 0, 0, 0);
        }
    };

    __syncthreads();               // colsS visible; pipeline starts clean
    const int nsteps = (cnt + 1) >> 1;
    stage(0, 0);
    if (nsteps > 1) stage(1, 1);
    int cur = 0;
    for (int js = 0; js < nsteps - 1; ++js) {
        vm_wait<5>();
        barrier();
        compute(cur);
        barrier();
        if (js + 2 < nsteps) stage(cur, js + 2);
        cur ^= 1;
    }
    vm_wait<0>();
    barrier();
    compute(cur);

    const int fq = l >> 4;
    #pragma unroll
    for (int i = 0; i < 2; ++i) {
        const int row0 = bm + wrow + i * 16 + fq * 4;
        #pragma unroll
        for (int jj = 0; jj < 2; ++jj) {
            const int col = r * 32 + jj * 16 + fr;
            const float bv = b2[col];
            #pragma unroll
            for (int v = 0; v < 4; ++v) {
                float rv = fmaxf(acc[i][jj][v] + bv, 0.f);
                h2[(size_t)(row0 + v) * 2048 + col] = f2bf(rv);
            }
        }
    }
}

// ---------------------------------------------------------------------------
extern "C" void kernel_launch(void* const* d_in, const int* in_sizes, int n_in,
                              void* d_out, int out_size, void* d_ws, size_t ws_size,
                              hipStream_t stream) {
    const float* x    = (const float*)d_in[0];   // 2048x1024
    const float* W1   = (const float*)d_in[1];   // 2048x1024
    const float* b1   = (const float*)d_in[2];   // 2048
    const int*   crow = (const int*)d_in[3];     // 65
    const int*   cols = (const int*)d_in[4];     // 2048
    const float* vals = (const float*)d_in[5];   // 2048x32x32
    const float* b2   = (const float*)d_in[6];   // 2048
    const float* W3   = (const float*)d_in[7];   // 1024x2048
    const float* b3   = (const float*)d_in[8];   // 1024
    float* out = (float*)d_out;                  // 2048x1024 f32

    const int NE = 2 * 1024 * 1024;
    unsigned short* xb  = (unsigned short*)d_ws;         // [0,  4MB)
    unsigned short* w1b = xb  + NE;                      // [4,  8MB)
    unsigned short* w3b = w1b + NE;                      // [8, 12MB)
    unsigned short* vb  = w3b + NE;                      // [12,16MB)
    unsigned short* hb  = vb  + NE;                      // [16,24MB)
    unsigned short* h2b = hb  + 2 * NE;                  // [24,32MB)

    cvt4<<<8192, 256, 0, stream>>>(x, W1, W3, vals, xb, w1b, w3b, vb);

    // L1: h = relu(x @ W1^T + b1)  M=2048 N=2048 K=1024, tile 128x64,
    // grid 512 (2 blocks/CU), PIPE=3 (72KB LDS)  — R8-exact
    gemm_bt<128, 64, 2, 1, 3, 1, 1><<<512, 256, 0, stream>>>(
        xb, w1b, b1, hb, nullptr, 2048, 2048, 1024);
    // L2: BSR + relu, grid 1024 (4 blocks/CU)  — R8-exact
    bsr_layer<<<1024, 256, 0, stream>>>(hb, crow, cols, vb, b2, h2b);
    // L3: out = h2 @ W3^T + b3  M=2048 N=1024 K=2048, tile 64x32,
    // grid 32x32 = 1024 blocks (4 blocks/CU), NO split-K, direct f32+bias,
    // PIPE=2 (24KB LDS)
    gemm_bt<64, 32, 4, 1, 2, 0, 0><<<1024, 256, 0, stream>>>(
        h2b, w3b, b3, out, nullptr, 2048, 1024, 2048);

    (void)in_sizes; (void)n_in; (void)out_size; (void)ws_size;
}

// Round 12
// 76.635 us; speedup vs baseline: 1.1289x; 1.0045x over previous
//
#include <hip/hip_runtime.h>
#include <hip/hip_bf16.h>

// ---------------------------------------------------------------------------
// BlockedMLP: out = (relu(bsr(relu(x@W1^T+b1))+b2)) @ W3^T + b3
// B=2048, IN=1024, H=2048, OUT=1024, BS=32, RB=CB=64, 32 blocks/row
// Round 12: R11 base (best, 77.0us). Single delta: L1 = 64x64 tile, PIPE=2,
// grid 1024 -> 5 blocks/CU (was 128x64 @ 2/CU). Occupancy has been the only
// consistently-positive lever (R3/R6/R11); intensity loss (42.7->32
// MAC/elem) is L2-served (per-XCD set ~4.5MB).
// Ruled out: fp8 (absmax ~16x bf16 = 0.06 > 0.019 threshold).
// ---------------------------------------------------------------------------

typedef __attribute__((ext_vector_type(8))) short bf16x8;
typedef __attribute__((ext_vector_type(4))) float f32x4;

__device__ __forceinline__ unsigned short f2bf(float f) {
    union { float f; unsigned int u; } c; c.f = f;
    unsigned int u = c.u;
    u += 0x7fffu + ((u >> 16) & 1u);   // round-to-nearest-even
    return (unsigned short)(u >> 16);
}

__device__ __forceinline__ void async16(const void* g, void* l) {
    __builtin_amdgcn_global_load_lds(
        (const __attribute__((address_space(1))) void*)g,
        (__attribute__((address_space(3))) void*)l,
        16, 0, 0);
}

template<int N>
__device__ __forceinline__ void vm_wait() {
    asm volatile("s_waitcnt vmcnt(%0)" :: "n"(N) : "memory");
}
__device__ __forceinline__ void barrier() {
    asm volatile("" ::: "memory");
    __builtin_amdgcn_s_barrier();
    asm volatile("" ::: "memory");
}

// ---------------------------------------------------------------------------
// fused f32 -> bf16 conversion of all 4 inputs (each exactly 2^21 elems)
// ---------------------------------------------------------------------------
__global__ __launch_bounds__(256) void cvt4(
    const float* __restrict__ x,  const float* __restrict__ w1,
    const float* __restrict__ w3, const float* __restrict__ v,
    unsigned short* __restrict__ xb,  unsigned short* __restrict__ w1b,
    unsigned short* __restrict__ w3b, unsigned short* __restrict__ vb)
{
    const int NE = 1 << 21;
    int e = (blockIdx.x * 256 + threadIdx.x) * 4;
    int a = e >> 21;                 // uniform within a block
    int off = e & (NE - 1);
    const float* src = (a == 0) ? x : (a == 1) ? w1 : (a == 2) ? w3 : v;
    unsigned short* dst = (a == 0) ? xb : (a == 1) ? w1b : (a == 2) ? w3b : vb;
    float4 vv = *reinterpret_cast<const float4*>(src + off);
    ushort4 o;
    o.x = f2bf(vv.x); o.y = f2bf(vv.y); o.z = f2bf(vv.z); o.w = f2bf(vv.w);
    *reinterpret_cast<ushort4*>(dst + off) = o;
}

// ---------------------------------------------------------------------------
// bf16 GEMM, B^T form: C[M,N] = A[M,K] x B[N,K]^T (+ bias, relu).
// BM x BN tile, BK=64, 256 threads = 4 waves (2x2), PIPE-deep LDS buffers,
// counted-vmcnt pipeline (PIPE-1 stages in flight across barriers),
// XOR swizzle chunk^(row&7) on staging-source + ds_read.
// 1-D grid, XCD-pinned decode.
// OUTMODE: 0 = f32+bias, 1 = bf16+bias, 2 = f32 partial (no bias).
// ---------------------------------------------------------------------------
template<int BM, int BN, int MCL, int KSPLIT, int PIPE, int RELU, int OUTMODE>
__global__ __launch_bounds__(256) void gemm_bt(
    const unsigned short* __restrict__ A,
    const unsigned short* __restrict__ B,
    const float* __restrict__ bias,
    void* __restrict__ C0,
    void* __restrict__ C1,
    int M, int N, int K)
{
    constexpr int BK = 64;                 // elems; 128B per row
    constexpr int MR = BM / 32;            // MFMA frag repeats per wave
    constexpr int NR = BN / 32;
    constexpr int AI = BM / 32;            // staging instrs per thread (A)
    constexpr int BI = BN / 32;
    constexpr int LPS = AI + BI;           // loads per thread per stage
    __shared__ unsigned short As[PIPE][BM * BK];
    __shared__ unsigned short Bs[PIPE][BN * BK];

    const int t = threadIdx.x;
    const int w = t >> 6;
    const int l = t & 63;

    // XCD-pinned tile decode (+ optional K-split)
    const int id = blockIdx.x;
    const int xcd = id & 7;
    int j = id >> 3;
    int ks = 0;
    if (KSPLIT == 2) { ks = j & 1; j >>= 1; }
    const int mt = xcd * MCL + (j & (MCL - 1));
    const int nt = j / MCL;
    const int bm = mt * BM;
    const int bn = nt * BN;
    const int kb = ks * (K / KSPLIT);

    const int wm = (w >> 1) * (BM / 2);
    const int wn = (w & 1) * (BN / 2);

    f32x4 acc[MR][NR];
    #pragma unroll
    for (int i = 0; i < MR; ++i)
        #pragma unroll
        for (int jj = 0; jj < NR; ++jj)
            acc[i][jj] = (f32x4){0.f, 0.f, 0.f, 0.f};

    // staging: instr i of wave w covers tile rows w*(BM/4)+i*8 + (l>>3);
    // lane chunk (l&7); swizzled source chunk = (l&7) ^ (row&7), row&7==l>>3
    const int arow = bm + w * (BM / 4) + (l >> 3);
    const int brow = bn + w * (BN / 4) + (l >> 3);
    const int scol = ((l & 7) ^ (l >> 3)) * 8;   // elems

    const int fr = l & 15;       // fragment row (within 16)
    const int kg = l >> 4;       // k-group
    const int fq = l >> 4;

    auto stage = [&](int buf, int kt) {
        const int k0 = kb + kt * BK;
        #pragma unroll
        for (int i = 0; i < AI; ++i)
            async16(A + (size_t)(arow + i * 8) * K + k0 + scol,
                    &As[buf][(w * (BM / 4) + i * 8) * BK]);
        #pragma unroll
        for (int i = 0; i < BI; ++i)
            async16(B + (size_t)(brow + i * 8) * K + k0 + scol,
                    &Bs[buf][(w * (BN / 4) + i * 8) * BK]);
    };

    auto compute = [&](int buf) {
        #pragma unroll
        for (int kk = 0; kk < 2; ++kk) {
            const int pc = ((kk * 4 + kg) ^ (fr & 7)) * 8;  // swizzled chunk
            bf16x8 af[MR], bg[NR];
            #pragma unroll
            for (int i = 0; i < MR; ++i)
                af[i] = *reinterpret_cast<const bf16x8*>(
                    &As[buf][(wm + i * 16 + fr) * BK + pc]);
            #pragma unroll
            for (int jj = 0; jj < NR; ++jj)
                bg[jj] = *reinterpret_cast<const bf16x8*>(
                    &Bs[buf][(wn + jj * 16 + fr) * BK + pc]);
            #pragma unroll
            for (int i = 0; i < MR; ++i)
                #pragma unroll
                for (int jj = 0; jj < NR; ++jj)
                    acc[i][jj] = __builtin_amdgcn_mfma_f32_16x16x32_bf16(
                        af[i], bg[jj], acc[i][jj], 0, 0, 0);
        }
    };

    const int nK = (K / KSPLIT) >> 6;
    stage(0, 0);
    stage(1, 1);
    if (PIPE == 3) stage(2, 2);
    int cur = 0;
    for (int kt = 0; kt < nK; ++kt) {
        if (PIPE == 3) {
            if (kt < nK - 2)       vm_wait<2 * LPS>();
            else if (kt == nK - 2) vm_wait<LPS>();
            else                   vm_wait<0>();
        } else {
            if (kt < nK - 1)       vm_wait<LPS>();
            else                   vm_wait<0>();
        }
        barrier();                 // all waves' buf[cur] loads drained
        compute(cur);
        if (kt + PIPE < nK) {
            barrier();             // WAR: all waves done reading buf[cur]
            stage(cur, kt + PIPE); // these loads span PIPE-1 iterations
        } else if (kt + 1 < nK) {
            barrier();
        }
        cur = (cur == PIPE - 1) ? 0 : cur + 1;
    }

    // epilogue: C/D layout col = l&15, row = (l>>4)*4 + v
    #pragma unroll
    for (int i = 0; i < MR; ++i) {
        const int row0 = bm + wm + i * 16 + fq * 4;
        #pragma unroll
        for (int jj = 0; jj < NR; ++jj) {
            const int col = bn + wn + jj * 16 + fr;
            const float bv = (OUTMODE == 2) ? 0.f : bias[col];
            #pragma unroll
            for (int v = 0; v < 4; ++v) {
                float r = acc[i][jj][v] + bv;
                if (RELU) r = fmaxf(r, 0.f);
                const size_t off = (size_t)(row0 + v) * N + col;
                if (OUTMODE == 1)
                    ((unsigned short*)C0)[off] = f2bf(r);
                else
                    ((float*)(ks ? C1 : C0))[off] = r;
            }
        }
    }
}

// ---------------------------------------------------------------------------
// BSR layer: 2 nnz blocks per K-step (K-concat), counted-vmcnt pipeline.
// 1-D grid 1024 (4 blocks/CU), XCD-pinned: xcd owns batch-tiles {2x, 2x+1}.
// LDS rows 128B, XOR-swizzled. Wave w owns batch rows w*32..+31 (2x2 frags).
// (R8 structure kept verbatim.)
// ---------------------------------------------------------------------------
__global__ __launch_bounds__(256) void bsr_layer(
    const unsigned short* __restrict__ h,     // 2048 x 2048 bf16
    const int* __restrict__ crow,
    const int* __restrict__ cols,
    const unsigned short* __restrict__ vals,  // nnz x 32 x 32 bf16
    const float* __restrict__ b2,
    unsigned short* __restrict__ h2)          // 2048 x 2048 bf16
{
    __shared__ unsigned short Hs[2][128 * 64];
    __shared__ unsigned short Vs[2][32 * 64];
    __shared__ int colsS[64];
    const int t = threadIdx.x;
    const int w = t >> 6;
    const int l = t & 63;

    const int id = blockIdx.x;
    const int xcd = id & 7;
    const int j2 = id >> 3;
    const int bt = xcd * 2 + (j2 & 1);
    const int r  = j2 >> 1;
    const int bm = bt * 128;

    const int s = crow[r];
    const int cnt = crow[r + 1] - s;
    const int wrow = w * 32;

    if (t < cnt) colsS[t] = cols[s + t];

    f32x4 acc[2][2];
    #pragma unroll
    for (int i = 0; i < 2; ++i)
        #pragma unroll
        for (int jj = 0; jj < 2; ++jj)
            acc[i][jj] = (f32x4){0.f, 0.f, 0.f, 0.f};

    const int fr = l & 15;
    const int kg = l >> 4;
    const int lr = l >> 3;               // staging row-in-group
    const int sc = (l & 7) ^ lr;         // swizzled source chunk

    auto stage = [&](int buf, int js) {
        const int n0 = s + 2 * js;
        const bool tail = (2 * js + 1 >= cnt);
        const int c0 = colsS[2 * js];
        const int c1 = tail ? c0 : colsS[2 * js + 1];
        const int n1 = tail ? n0 : n0 + 1;
        #pragma unroll
        for (int i = 0; i < 4; ++i) {
            const int row = bm + w * 32 + i * 8 + lr;
            const int col = (sc & 4) ? c1 * 32 + (sc & 3) * 8 : c0 * 32 + sc * 8;
            async16(h + (size_t)row * 2048 + col,
                    &Hs[buf][(w * 32 + i * 8) * 64]);
        }
        const int vrow = w * 8 + lr;
        if (!tail || !(sc & 4)) {
            const unsigned short* src =
                vals + (size_t)((sc & 4) ? n1 : n0) * 1024 + vrow * 32 + (sc & 3) * 8;
            async16(src, &Vs[buf][(w * 8) * 64]);
        } else {
            bf16x8 z = (bf16x8){0,0,0,0,0,0,0,0};
            *reinterpret_cast<bf16x8*>(&Vs[buf][vrow * 64 + (l & 7) * 8]) = z;
        }
    };

    auto compute = [&](int buf) {
        #pragma unroll
        for (int kk = 0; kk < 2; ++kk) {
            const int pc = ((kk * 4 + kg) ^ (fr & 7)) * 8;
            bf16x8 af[2], bg[2];
            #pragma unroll
            for (int i = 0; i < 2; ++i)
                af[i] = *reinterpret_cast<const bf16x8*>(
                    &Hs[buf][(wrow + i * 16 + fr) * 64 + pc]);
            #pragma unroll
            for (int jj = 0; jj < 2; ++jj)
                bg[jj] = *reinterpret_cast<const bf16x8*>(
                    &Vs[buf][(jj * 16 + fr) * 64 + pc]);
            #pragma unroll
            for (int i = 0; i < 2; ++i)
                #pragma unroll
                for (int jj = 0; jj < 2; ++jj)
                    acc[i][jj] = __builtin_amdgcn_mfma_f32_16x16x32_bf16(
                        af[i], bg[jj], acc[i][jj], 0, 0, 0);
        }
    };

    __syncthreads();               // colsS visible; pipeline starts clean
    const int nsteps = (cnt + 1) >> 1;
    stage(0, 0);
    if (nsteps > 1) stage(1, 1);
    int cur = 0;
    for (int js = 0; js < nsteps - 1; ++js) {
        vm_wait<5>();
        barrier();
        compute(cur);
        barrier();
        if (js + 2 < nsteps) stage(cur, js + 2);
        cur ^= 1;
    }
    vm_wait<0>();
    barrier();
    compute(cur);

    const int fq = l >> 4;
    #pragma unroll
    for (int i = 0; i < 2; ++i) {
        const int row0 = bm + wrow + i * 16 + fq * 4;
        #pragma unroll
        for (int jj = 0; jj < 2; ++jj) {
            const int col = r * 32 + jj * 16 + fr;
            const float bv = b2[col];
            #pragma unroll
            for (int v = 0; v < 4; ++v) {
                float rv = fmaxf(acc[i][jj][v] + bv, 0.f);
                h2[(size_t)(row0 + v) * 2048 + col] = f2bf(rv);
            }
        }
    }
}

// ---------------------------------------------------------------------------
extern "C" void kernel_launch(void* const* d_in, const int* in_sizes, int n_in,
                              void* d_out, int out_size, void* d_ws, size_t ws_size,
                              hipStream_t stream) {
    const float* x    = (const float*)d_in[0];   // 2048x1024
    const float* W1   = (const float*)d_in[1];   // 2048x1024
    const float* b1   = (const float*)d_in[2];   // 2048
    const int*   crow = (const int*)d_in[3];     // 65
    const int*   cols = (const int*)d_in[4];     // 2048
    const float* vals = (const float*)d_in[5];   // 2048x32x32
    const float* b2   = (const float*)d_in[6];   // 2048
    const float* W3   = (const float*)d_in[7];   // 1024x2048
    const float* b3   = (const float*)d_in[8];   // 1024
    float* out = (float*)d_out;                  // 2048x1024 f32

    const int NE = 2 * 1024 * 1024;
    unsigned short* xb  = (unsigned short*)d_ws;         // [0,  4MB)
    unsigned short* w1b = xb  + NE;                      // [4,  8MB)
    unsigned short* w3b = w1b + NE;                      // [8, 12MB)
    unsigned short* vb  = w3b + NE;                      // [12,16MB)
    unsigned short* hb  = vb  + NE;                      // [16,24MB)
    unsigned short* h2b = hb  + 2 * NE;                  // [24,32MB)

    cvt4<<<8192, 256, 0, stream>>>(x, W1, W3, vals, xb, w1b, w3b, vb);

    // L1: h = relu(x @ W1^T + b1)  M=2048 N=2048 K=1024, tile 64x64,
    // grid 32x32 = 1024 blocks (5 blocks/CU, 32KB LDS), PIPE=2
    gemm_bt<64, 64, 4, 1, 2, 1, 1><<<1024, 256, 0, stream>>>(
        xb, w1b, b1, hb, nullptr, 2048, 2048, 1024);
    // L2: BSR + relu, grid 1024 (4 blocks/CU)  — R8-exact
    bsr_layer<<<1024, 256, 0, stream>>>(hb, crow, cols, vb, b2, h2b);
    // L3: out = h2 @ W3^T + b3  M=2048 N=1024 K=2048, tile 64x32,
    // grid 32x32 = 1024 blocks (4 blocks/CU), direct f32+bias, PIPE=2
    gemm_bt<64, 32, 4, 1, 2, 0, 0><<<1024, 256, 0, stream>>>(
        h2b, w3b, b3, out, nullptr, 2048, 1024, 2048);

    (void)in_sizes; (void)n_in; (void)out_size; (void)ws_size;
}